// Round 17
// baseline (21.192 us; speedup 1.0000x reference)
//
#include <hip/hip_runtime.h>
#include <math.h>

#define NPTS 11
#define METRIC_FLOOR 0.1f

// Raw grid: 32 x 32, point ri at c = (ri-2)/27.
#define RAWN 32
#define RAW2 1024
// Hermite interior grid: 30 x 30, point i at c = (i-1)/27.
#define NG 30
#define SCALE_G 27.0f
#define INV_SCALE (1.0f / 27.0f)

typedef float v2f __attribute__((ext_vector_type(2)));

#define L2E 1.44269504088896340736f
#define LN2 0.69314718055994530942f

struct MW {
    float w1c[16], w1l[16], b1v[16], b2v[16], w3v[16];
};

static __device__ __forceinline__ float fast_tanh(float x) {
    float e = __builtin_amdgcn_exp2f(x * (2.0f * L2E));
    return fmaf(-2.0f, __builtin_amdgcn_rcpf(e + 1.0f), 1.0f);
}

// Value-only metric eval: sqrt(softplus(MLP(c,lam)) + floor).
static __device__ __forceinline__ float metric_s(
    float c, float lam, const MW& mw, const float* __restrict__ sW2, float b3v)
{
    float h1[16];
#pragma unroll
    for (int j = 0; j < 16; ++j) {
        float u = fmaf(c, mw.w1c[j], fmaf(lam, mw.w1l[j], mw.b1v[j]));
        h1[j] = fast_tanh(u);
    }
    v2f U[8];
#pragma unroll
    for (int jp = 0; jp < 8; ++jp) U[jp] = (v2f){mw.b2v[2*jp], mw.b2v[2*jp+1]};
#pragma unroll 2
    for (int i = 0; i < 16; ++i) {
        const float4* wrow4 = reinterpret_cast<const float4*>(sW2 + i * 16);
        v2f hh = (v2f){h1[i], h1[i]};
#pragma unroll
        for (int q4 = 0; q4 < 4; ++q4) {
            float4 w4 = wrow4[q4];
            U[2*q4]   = __builtin_elementwise_fma((v2f){w4.x, w4.y}, hh, U[2*q4]);
            U[2*q4+1] = __builtin_elementwise_fma((v2f){w4.z, w4.w}, hh, U[2*q4+1]);
        }
    }
    float z = b3v;
#pragma unroll
    for (int jp = 0; jp < 8; ++jp)
#pragma unroll
        for (int k = 0; k < 2; ++k)
            z = fmaf(fast_tanh(U[jp][k]), mw.w3v[2*jp+k], z);
    float az = fabsf(z);
    float em = __builtin_amdgcn_exp2f(-az * L2E);
    float sp = fmaxf(z, 0.0f) + __builtin_amdgcn_logf(1.0f + em) * LN2;
    return sqrtf(sp + METRIC_FLOOR);
}

// Fused bicubic Hermite eval: F and d = dF/dX (grid units). sqrt(g) = d/h.
static __device__ __forceinline__ void feval(
    const float4* __restrict__ r0, const float4* __restrict__ r1,
    float hy0, float hy1, float hy2, float hy3, float X,
    float& F_out, float& d_out)
{
    float fx = floorf(X);
    fx = fminf(fmaxf(fx, 0.0f), (float)(NG - 2));
    float tx = X - fx;
    int i0 = (int)fx;
    float t2 = tx * tx, t3 = t2 * tx;
    float h00 = fmaf(2.0f, t3, fmaf(-3.0f, t2, 1.0f));
    float h10 = t3 - 2.0f * t2 + tx;
    float h01 = fmaf(-2.0f, t3, 3.0f * t2);
    float h11 = t3 - t2;
    float d00 = 6.0f * (t2 - tx);
    float d10 = fmaf(3.0f, t2, fmaf(-4.0f, tx, 1.0f));
    float d01 = -d00;
    float d11 = fmaf(3.0f, t2, -2.0f * tx);

    float4 a0 = r0[i0], b0 = r0[i0 + 1];
    float4 a1 = r1[i0], b1 = r1[i0 + 1];
    const float h = INV_SCALE;

    float Fc0  = fmaf(h00, a0.x, fmaf(h10, h * a0.y, fmaf(h01, b0.x, h11 * (h * b0.y))));
    float dF0  = fmaf(d00, a0.x, fmaf(d10, h * a0.y, fmaf(d01, b0.x, d11 * (h * b0.y))));
    float FY0  = fmaf(h00, a0.z, fmaf(h10, h * a0.w, fmaf(h01, b0.z, h11 * (h * b0.w))));
    float dFY0 = fmaf(d00, a0.z, fmaf(d10, h * a0.w, fmaf(d01, b0.z, d11 * (h * b0.w))));
    float Fc1  = fmaf(h00, a1.x, fmaf(h10, h * a1.y, fmaf(h01, b1.x, h11 * (h * b1.y))));
    float dF1  = fmaf(d00, a1.x, fmaf(d10, h * a1.y, fmaf(d01, b1.x, d11 * (h * b1.y))));
    float FY1  = fmaf(h00, a1.z, fmaf(h10, h * a1.w, fmaf(h01, b1.z, h11 * (h * b1.w))));
    float dFY1 = fmaf(d00, a1.z, fmaf(d10, h * a1.w, fmaf(d01, b1.z, d11 * (h * b1.w))));

    F_out = fmaf(hy0, Fc0, fmaf(hy1, FY0, fmaf(hy2, Fc1, hy3 * FY1)));
    d_out = fmaf(hy0, dF0, fmaf(hy1, dFY0, fmaf(hy2, dF1, hy3 * dFY1)));
}

// ---------------------------------------------------------------------------
// Single dispatch: in-block table build (value-only evals + shfl scan +
// Hermite assembly) + independent-node inversion + decoder.
// ---------------------------------------------------------------------------
extern "C" __global__ __launch_bounds__(256, 1)
void geodesic_kernel(const float* __restrict__ gc0, const float* __restrict__ gc1,
                     const float* __restrict__ glam,
                     const float* __restrict__ W1, const float* __restrict__ b1,
                     const float* __restrict__ W2, const float* __restrict__ b2,
                     const float* __restrict__ W3, const float* __restrict__ b3,
                     const float* __restrict__ D1, const float* __restrict__ d1,
                     const float* __restrict__ D2, const float* __restrict__ d2,
                     float* __restrict__ out, int n)
{
    __shared__ __align__(16) float  sW2[256];      //  1 KB
    __shared__ __align__(16) float  ls[RAW2];      //  4 KB  sqrt(g)
    __shared__ __align__(16) float  lF[RAW2];      //  4 KB  prefix F
    __shared__ __align__(16) float4 sH[NG * NG];   // 14.4 KB Hermite
    __shared__ __align__(16) float  sD1[6 * 64];
    __shared__ __align__(16) float  sd1[64];
    __shared__ __align__(16) float  sD2[64];

    const int t = threadIdx.x;

    // ---- Stage weights (pipelined loads), MW -> SGPRs ----------------------
    sW2[t] = W2[t];
    for (int i = t; i < 384; i += 256) sD1[i] = D1[i];
    if (t < 64) sd1[t] = d1[t];
    if (t >= 64 && t < 128) sD2[t - 64] = D2[t - 64];

    MW mw;
#pragma unroll
    for (int j = 0; j < 16; ++j) {
        mw.w1c[j] = W1[j];
        mw.w1l[j] = W1[16 + j];
        mw.b1v[j] = b1[j];
        mw.b2v[j] = b2[j];
        mw.w3v[j] = W3[j];
    }
    const float b3v = b3[0];
    const float d2v = d2[0];
    __syncthreads();

    // ---- Build sqrt(g) raw grid: 4 value-only evals per thread -------------
    float sv[4];
#pragma unroll
    for (int k = 0; k < 4; ++k) {
        const int p  = t + k * 256;
        const int ri = p & (RAWN - 1);
        const int rj = p >> 5;
        sv[k] = metric_s((float)(ri - 2) * INV_SCALE,
                         (float)(rj - 2) * INV_SCALE, mw, sW2, b3v);
        ls[p] = sv[k];
    }

    // ---- Row prefix F = int sqrt(g) dc: 4-pt value-only quadrature ---------
    // (rows are 32-lane shfl segments; border intervals use 3-pt one-sided)
    {
        const float h = INV_SCALE;
#pragma unroll
        for (int k = 0; k < 4; ++k) {
            const int p   = t + k * 256;
            const int col = p & (RAWN - 1);
            float s   = sv[k];
            float sm1 = __shfl_up(s, 1, 32);
            float sm2 = __shfl_up(s, 2, 32);
            float sp1 = __shfl_down(s, 1, 32);
            float inc;
            if (col == 0)        inc = 0.0f;
            else if (col == 1)   inc = h * (5.0f * sm1 + 8.0f * s - sp1) * (1.0f / 12.0f);
            else if (col == 31)  inc = h * (-sm2 + 8.0f * sm1 + 5.0f * s) * (1.0f / 12.0f);
            else                 inc = h * (13.0f * (sm1 + s) - sm2 - sp1) * (1.0f / 24.0f);
            float F = inc;
#pragma unroll
            for (int d = 1; d < 32; d <<= 1) {
                float o = __shfl_up(F, (unsigned)d, 32);
                if (col >= d) F += o;
            }
            lF[p] = F;
        }
    }
    __syncthreads();

    // ---- Hermite assembly (F, s, F_lam, s_lam), 900 interior points --------
    for (int p = t; p < NG * NG; p += 256) {
        const int ii = p % NG, jj = p / NG;
        const int ri = ii + 1, rj = jj + 1;
        float Fv = lF[rj * RAWN + ri];
        float sq = ls[rj * RAWN + ri];
        float FY = 0.5f * (lF[(rj + 1) * RAWN + ri] - lF[(rj - 1) * RAWN + ri]);
        float sY = 0.5f * (ls[(rj + 1) * RAWN + ri] - ls[(rj - 1) * RAWN + ri]);
        sH[p] = make_float4(Fv, sq, FY, sY);
    }
    __syncthreads();

    const int idx = blockIdx.x * blockDim.x + t;
    if (idx >= n) return;

    const float c0  = gc0[idx];
    const float c1  = gc1[idx];
    const float lam = glam[idx];

    // lam-direction Hermite row + weights.
    float sy = fmaf(lam, SCALE_G, 1.0f);
    float fy = fminf(fmaxf(floorf(sy), 0.0f), (float)(NG - 2));
    float ty = sy - fy;
    int j0 = (int)fy;
    float ty2 = ty * ty, ty3 = ty2 * ty;
    const float hy0 = fmaf(2.0f, ty3, fmaf(-3.0f, ty2, 1.0f));
    const float hy1 = ty3 - 2.0f * ty2 + ty;
    const float hy2 = fmaf(-2.0f, ty3, 3.0f * ty2);
    const float hy3 = ty3 - ty2;
    const float4* gr0 = sH + j0 * NG;
    const float4* gr1 = gr0 + NG;

    // Endpoints.
    const float X0 = fmaf(c0, SCALE_G, 1.0f);
    const float X1 = fmaf(c1, SCALE_G, 1.0f);
    float F0, dd0, F1, dd1;
    feval(gr0, gr1, hy0, hy1, hy2, hy3, X0, F0, dd0);
    feval(gr0, gr1, hy0, hy1, hy2, hy3, X1, F1, dd1);
    const float L = F1 - F0;

    // 9 interior nodes, independent; 3 Newton iterations each.
    float X[9], dlast[9];
#pragma unroll
    for (int i = 0; i < 9; ++i)
        X[i] = fmaf((float)(i + 1) * 0.1f, X1 - X0, X0);
#pragma unroll
    for (int it = 0; it < 3; ++it) {
#pragma unroll
        for (int i = 0; i < 9; ++i) {
            float F, d;
            feval(gr0, gr1, hy0, hy1, hy2, hy3, X[i], F, d);
            float Ti = fmaf((float)(i + 1) * 0.1f, L, F0);
            X[i] -= (F - Ti) * __builtin_amdgcn_rcpf(d);
            dlast[i] = d;
        }
    }

    // Stats: v_i = L*h/d_i ; plen = |c1-c0| ; cf = c1.
    const float Lh = L * INV_SCALE;
    float csum = c0 + c1;
    float r0e = __builtin_amdgcn_rcpf(dd0);
    float r1e = __builtin_amdgcn_rcpf(dd1);
    float rsum = r0e + r1e;
    float rmax = fmaxf(r0e, r1e);
#pragma unroll
    for (int i = 0; i < 9; ++i) {
        csum += (X[i] - 1.0f) * INV_SCALE;
        float r = __builtin_amdgcn_rcpf(dlast[i]);
        rsum += r;
        rmax = fmaxf(rmax, r);
    }
    const float vsum = Lh * rsum;
    const float vmax = fabsf(Lh) * rmax;
    const float plen = fabsf(c1 - c0);

    // Decoder.
    const float inv_npts = 1.0f / (float)NPTS;
    const float f0 = csum * inv_npts;
    const float f1 = c1;
    const float f2 = plen;
    const float f3 = vsum * inv_npts;
    const float f4 = vmax;
    const float f5 = lam;

    float acc = d2v;
#pragma unroll 4
    for (int j = 0; j < 64; ++j) {
        float u = sd1[j];
        u = fmaf(f0, sD1[0 * 64 + j], u);
        u = fmaf(f1, sD1[1 * 64 + j], u);
        u = fmaf(f2, sD1[2 * 64 + j], u);
        u = fmaf(f3, sD1[3 * 64 + j], u);
        u = fmaf(f4, sD1[4 * 64 + j], u);
        u = fmaf(f5, sD1[5 * 64 + j], u);
        acc = fmaf(fast_tanh(u), sD2[j], acc);
    }
    out[idx] = acc;
}

extern "C" void kernel_launch(void* const* d_in, const int* in_sizes, int n_in,
                              void* d_out, int out_size, void* d_ws, size_t ws_size,
                              hipStream_t stream) {
    const float* c_source   = (const float*)d_in[0];
    const float* c_target   = (const float*)d_in[1];
    const float* wavelength = (const float*)d_in[2];
    const float* W1 = (const float*)d_in[3];
    const float* b1 = (const float*)d_in[4];
    const float* W2 = (const float*)d_in[5];
    const float* b2 = (const float*)d_in[6];
    const float* W3 = (const float*)d_in[7];
    const float* b3 = (const float*)d_in[8];
    const float* D1 = (const float*)d_in[9];
    const float* d1 = (const float*)d_in[10];
    const float* D2 = (const float*)d_in[11];
    const float* d2 = (const float*)d_in[12];
    float* out = (float*)d_out;

    const int n = in_sizes[0];
    const int block = 256;
    const int grid  = (n + block - 1) / block;
    hipLaunchKernelGGL(geodesic_kernel, dim3(grid), dim3(block), 0, stream,
                       c_source, c_target, wavelength,
                       W1, b1, W2, b2, W3, b3, D1, d1, D2, d2, out, n);
}

// Round 18
// 19.395 us; speedup vs baseline: 1.0926x; 1.0926x over previous
//
#include <hip/hip_runtime.h>
#include <math.h>

#define NPTS 11
#define METRIC_FLOOR 0.1f

// Raw grid: 32 x 32, point ri at c = (ri-2)/27.
#define RAWN 32
#define RAW2 1024
// Hermite interior grid: 30 x 30, point i at c = (i-1)/27.
#define NG 30
#define SCALE_G 27.0f
#define INV_SCALE (1.0f / 27.0f)

// d_ws float offsets
#define WS_S  0        // sqrt(g) raw, 1024 floats
#define WS_SP 1024     // d sqrt(g)/dc raw, 1024 floats

typedef float v2f __attribute__((ext_vector_type(2)));

#define L2E 1.44269504088896340736f
#define LN2 0.69314718055994530942f

struct MW {
    float w1c[16], w1l[16], b1v[16], b2v[16], w3v[16];
};

static __device__ __forceinline__ float fast_tanh(float x) {
    float e = __builtin_amdgcn_exp2f(x * (2.0f * L2E));
    return fmaf(-2.0f, __builtin_amdgcn_rcpf(e + 1.0f), 1.0f);
}

// ---------------------------------------------------------------------------
// K1: (sqrt(g), d sqrt(g)/dc) at each raw point (full-accuracy MLP).
// ---------------------------------------------------------------------------
extern "C" __global__ void table_raw_kernel(
    const float* __restrict__ W1, const float* __restrict__ b1,
    const float* __restrict__ W2, const float* __restrict__ b2,
    const float* __restrict__ W3, const float* __restrict__ b3,
    float* __restrict__ ws)
{
    __shared__ __align__(16) float sW2[256];
    const int t = threadIdx.x;
    sW2[t] = W2[t];
    __syncthreads();

    const int p = blockIdx.x * 256 + t;
    if (p >= RAW2) return;

    MW mw;
#pragma unroll
    for (int j = 0; j < 16; ++j) {
        mw.w1c[j] = W1[j];
        mw.w1l[j] = W1[16 + j];
        mw.b1v[j] = b1[j];
        mw.b2v[j] = b2[j];
        mw.w3v[j] = W3[j];
    }
    const float b3v = b3[0];

    const int ri = p & (RAWN - 1), rj = p >> 5;
    const float c   = (float)(ri - 2) * INV_SCALE;
    const float lam = (float)(rj - 2) * INV_SCALE;

    float h1[16], p1[16];
#pragma unroll
    for (int k = 0; k < 16; ++k) {
        float a  = mw.w1c[k];
        float u  = fmaf(c, a, fmaf(lam, mw.w1l[k], mw.b1v[k]));
        float t0 = fast_tanh(u);
        float s  = fmaf(-t0, t0, 1.0f);
        h1[k] = t0;
        p1[k] = s * a;
    }
    v2f U[8], DU[8];
#pragma unroll
    for (int jp = 0; jp < 8; ++jp) {
        U[jp]  = (v2f){mw.b2v[2*jp], mw.b2v[2*jp+1]};
        DU[jp] = (v2f){0.0f, 0.0f};
    }
#pragma unroll 2
    for (int i2 = 0; i2 < 16; ++i2) {
        const float4* wrow4 = reinterpret_cast<const float4*>(sW2 + i2 * 16);
        v2f hh = (v2f){h1[i2], h1[i2]};
        v2f pp = (v2f){p1[i2], p1[i2]};
#pragma unroll
        for (int q4 = 0; q4 < 4; ++q4) {
            float4 w4 = wrow4[q4];
            v2f wa = (v2f){w4.x, w4.y};
            v2f wb = (v2f){w4.z, w4.w};
            int jp = 2 * q4;
            U[jp]    = __builtin_elementwise_fma(wa, hh, U[jp]);
            DU[jp]   = __builtin_elementwise_fma(wa, pp, DU[jp]);
            U[jp+1]  = __builtin_elementwise_fma(wb, hh, U[jp+1]);
            DU[jp+1] = __builtin_elementwise_fma(wb, pp, DU[jp+1]);
        }
    }
    float z = b3v, dz = 0.0f;
#pragma unroll
    for (int jp = 0; jp < 8; ++jp)
#pragma unroll
        for (int k = 0; k < 2; ++k) {
            float u  = U[jp][k];
            float du = DU[jp][k];
            float t0 = fast_tanh(u);
            float s  = fmaf(-t0, t0, 1.0f);
            float w3 = mw.w3v[2*jp+k];
            z  = fmaf(t0, w3, z);
            dz = fmaf(s * du, w3, dz);
        }
    float az  = fabsf(z);
    float em  = __builtin_amdgcn_exp2f(-az * L2E);
    float r1  = __builtin_amdgcn_rcpf(1.0f + em);
    float spv = fmaxf(z, 0.0f) + __builtin_amdgcn_logf(1.0f + em) * LN2;
    float sig = (z >= 0.0f) ? r1 : (1.0f - r1);
    float g   = spv + METRIC_FLOOR;
    float dg  = sig * dz;

    float s  = sqrtf(g);
    ws[WS_S  + p] = s;
    ws[WS_SP + p] = 0.5f * dg * __builtin_amdgcn_rcpf(s);
}

// ---------------------------------------------------------------------------
// Fused bicubic Hermite eval: F and d = dF/dX (grid units). sqrt(g) = d/h.
// ---------------------------------------------------------------------------
static __device__ __forceinline__ void feval(
    const float4* __restrict__ r0, const float4* __restrict__ r1,
    float hy0, float hy1, float hy2, float hy3, float X,
    float& F_out, float& d_out)
{
    float fx = floorf(X);
    fx = fminf(fmaxf(fx, 0.0f), (float)(NG - 2));
    float tx = X - fx;
    int i0 = (int)fx;
    float t2 = tx * tx, t3 = t2 * tx;
    float h00 = fmaf(2.0f, t3, fmaf(-3.0f, t2, 1.0f));
    float h10 = t3 - 2.0f * t2 + tx;
    float h01 = fmaf(-2.0f, t3, 3.0f * t2);
    float h11 = t3 - t2;
    float d00 = 6.0f * (t2 - tx);
    float d10 = fmaf(3.0f, t2, fmaf(-4.0f, tx, 1.0f));
    float d01 = -d00;
    float d11 = fmaf(3.0f, t2, -2.0f * tx);

    float4 a0 = r0[i0], b0 = r0[i0 + 1];
    float4 a1 = r1[i0], b1 = r1[i0 + 1];
    const float h = INV_SCALE;

    float Fc0  = fmaf(h00, a0.x, fmaf(h10, h * a0.y, fmaf(h01, b0.x, h11 * (h * b0.y))));
    float dF0  = fmaf(d00, a0.x, fmaf(d10, h * a0.y, fmaf(d01, b0.x, d11 * (h * b0.y))));
    float FY0  = fmaf(h00, a0.z, fmaf(h10, h * a0.w, fmaf(h01, b0.z, h11 * (h * b0.w))));
    float dFY0 = fmaf(d00, a0.z, fmaf(d10, h * a0.w, fmaf(d01, b0.z, d11 * (h * b0.w))));
    float Fc1  = fmaf(h00, a1.x, fmaf(h10, h * a1.y, fmaf(h01, b1.x, h11 * (h * b1.y))));
    float dF1  = fmaf(d00, a1.x, fmaf(d10, h * a1.y, fmaf(d01, b1.x, d11 * (h * b1.y))));
    float FY1  = fmaf(h00, a1.z, fmaf(h10, h * a1.w, fmaf(h01, b1.z, h11 * (h * b1.w))));
    float dFY1 = fmaf(d00, a1.z, fmaf(d10, h * a1.w, fmaf(d01, b1.z, d11 * (h * b1.w))));

    F_out = fmaf(hy0, Fc0, fmaf(hy1, FY0, fmaf(hy2, Fc1, hy3 * FY1)));
    d_out = fmaf(hy0, dF0, fmaf(hy1, dFY0, fmaf(hy2, dF1, hy3 * dFY1)));
}

// ---------------------------------------------------------------------------
// Main: in-block scan+assembly (K2 folded in) + node inversion + decoder.
// ---------------------------------------------------------------------------
extern "C" __global__ __launch_bounds__(256, 1)
void geodesic_kernel(const float* __restrict__ gc0, const float* __restrict__ gc1,
                     const float* __restrict__ glam,
                     const float* __restrict__ D1, const float* __restrict__ d1,
                     const float* __restrict__ D2, const float* __restrict__ d2,
                     const float* __restrict__ ws,
                     float* __restrict__ out, int n)
{
    __shared__ __align__(16) float  ls[RAW2];      // sqrt(g)        4 KB
    __shared__ __align__(16) float  lsp[RAW2];     // d sqrt(g)/dc   4 KB
    __shared__ __align__(16) float  lF[RAW2];      // prefix F       4 KB
    __shared__ __align__(16) float4 sH[NG * NG];   // Hermite        14.4 KB
    __shared__ __align__(16) float  sD1[6 * 64];
    __shared__ __align__(16) float  sd1[64];
    __shared__ __align__(16) float  sD2[64];

    const int t = threadIdx.x;

    // ---- Stage raw tables + decoder weights (pipelined: loads then writes) --
    {
        const float4* wsS4  = reinterpret_cast<const float4*>(ws + WS_S);
        const float4* wsSP4 = reinterpret_cast<const float4*>(ws + WS_SP);
        const float4* D1f   = reinterpret_cast<const float4*>(D1);
        const float4* d1f   = reinterpret_cast<const float4*>(d1);
        const float4* D2f   = reinterpret_cast<const float4*>(D2);

        float4 sv  = wsS4[t];
        float4 spv = wsSP4[t];
        float4 tail_d = make_float4(0.f, 0.f, 0.f, 0.f);
        if (t < 128) tail_d = (t < 96) ? D1f[t]
                             : (t < 112 ? d1f[t - 96] : D2f[t - 112]);

        reinterpret_cast<float4*>(ls)[t]  = sv;
        reinterpret_cast<float4*>(lsp)[t] = spv;
        if (t < 128) {
            if (t < 96)       reinterpret_cast<float4*>(sD1)[t]       = tail_d;
            else if (t < 112) reinterpret_cast<float4*>(sd1)[t - 96]  = tail_d;
            else              reinterpret_cast<float4*>(sD2)[t - 112] = tail_d;
        }
    }
    __syncthreads();

    // ---- Row prefix scan: F = int sqrt(g) dc (Hermite quadrature) ----------
    {
        const float h  = INV_SCALE;
        const float h2 = h * h * (1.0f / 12.0f);
#pragma unroll
        for (int k = 0; k < 4; ++k) {
            const int p = t + k * 256;
            const int col = p & (RAWN - 1);
            float s  = ls[p];
            float sp = lsp[p];
            float s_prev  = __shfl_up(s, 1, 32);
            float sp_prev = __shfl_up(sp, 1, 32);
            float F = (col == 0) ? 0.0f
                    : 0.5f * h * (s_prev + s) + h2 * (sp_prev - sp);
#pragma unroll
            for (int d = 1; d < 32; d <<= 1) {
                float o = __shfl_up(F, (unsigned)d, 32);
                if (col >= d) F += o;
            }
            lF[p] = F;
        }
    }
    __syncthreads();

    // ---- Hermite assembly (F, s, F_lam, s_lam), 900 interior points --------
    for (int p = t; p < NG * NG; p += 256) {
        const int ii = p % NG, jj = p / NG;
        const int ri = ii + 1, rj = jj + 1;
        float Fv = lF[rj * RAWN + ri];
        float sv = ls[rj * RAWN + ri];
        float FY = 0.5f * (lF[(rj + 1) * RAWN + ri] - lF[(rj - 1) * RAWN + ri]);
        float sY = 0.5f * (ls[(rj + 1) * RAWN + ri] - ls[(rj - 1) * RAWN + ri]);
        sH[p] = make_float4(Fv, sv, FY, sY);
    }
    __syncthreads();

    const int idx = blockIdx.x * blockDim.x + t;
    if (idx >= n) return;

    const float d2v = d2[0];
    const float c0  = gc0[idx];
    const float c1  = gc1[idx];
    const float lam = glam[idx];

    // lam-direction Hermite row + weights.
    float sy = fmaf(lam, SCALE_G, 1.0f);
    float fy = fminf(fmaxf(floorf(sy), 0.0f), (float)(NG - 2));
    float ty = sy - fy;
    int j0 = (int)fy;
    float ty2 = ty * ty, ty3 = ty2 * ty;
    const float hy0 = fmaf(2.0f, ty3, fmaf(-3.0f, ty2, 1.0f));
    const float hy1 = ty3 - 2.0f * ty2 + ty;
    const float hy2 = fmaf(-2.0f, ty3, 3.0f * ty2);
    const float hy3 = ty3 - ty2;
    const float4* gr0 = sH + j0 * NG;
    const float4* gr1 = gr0 + NG;

    // Endpoints.
    const float X0 = fmaf(c0, SCALE_G, 1.0f);
    const float X1 = fmaf(c1, SCALE_G, 1.0f);
    float F0, dd0, F1, dd1;
    feval(gr0, gr1, hy0, hy1, hy2, hy3, X0, F0, dd0);
    feval(gr0, gr1, hy0, hy1, hy2, hy3, X1, F1, dd1);
    const float L = F1 - F0;

    // 9 interior nodes, independent; 3 Newton iterations each.
    float X[9], dlast[9];
#pragma unroll
    for (int i = 0; i < 9; ++i)
        X[i] = fmaf((float)(i + 1) * 0.1f, X1 - X0, X0);
#pragma unroll
    for (int it = 0; it < 3; ++it) {
#pragma unroll
        for (int i = 0; i < 9; ++i) {
            float F, d;
            feval(gr0, gr1, hy0, hy1, hy2, hy3, X[i], F, d);
            float Ti = fmaf((float)(i + 1) * 0.1f, L, F0);
            X[i] -= (F - Ti) * __builtin_amdgcn_rcpf(d);
            dlast[i] = d;
        }
    }

    // Stats: v_i = L*h/d_i ; plen = |c1-c0| ; cf = c1.
    const float Lh = L * INV_SCALE;
    float csum = c0 + c1;
    float r0e = __builtin_amdgcn_rcpf(dd0);
    float r1e = __builtin_amdgcn_rcpf(dd1);
    float rsum = r0e + r1e;
    float rmax = fmaxf(r0e, r1e);
#pragma unroll
    for (int i = 0; i < 9; ++i) {
        csum += (X[i] - 1.0f) * INV_SCALE;
        float r = __builtin_amdgcn_rcpf(dlast[i]);
        rsum += r;
        rmax = fmaxf(rmax, r);
    }
    const float vsum = Lh * rsum;
    const float vmax = fabsf(Lh) * rmax;
    const float plen = fabsf(c1 - c0);

    // Decoder.
    const float inv_npts = 1.0f / (float)NPTS;
    const float f0 = csum * inv_npts;
    const float f1 = c1;
    const float f2 = plen;
    const float f3 = vsum * inv_npts;
    const float f4 = vmax;
    const float f5 = lam;

    float acc = d2v;
#pragma unroll 4
    for (int j = 0; j < 64; ++j) {
        float u = sd1[j];
        u = fmaf(f0, sD1[0 * 64 + j], u);
        u = fmaf(f1, sD1[1 * 64 + j], u);
        u = fmaf(f2, sD1[2 * 64 + j], u);
        u = fmaf(f3, sD1[3 * 64 + j], u);
        u = fmaf(f4, sD1[4 * 64 + j], u);
        u = fmaf(f5, sD1[5 * 64 + j], u);
        acc = fmaf(fast_tanh(u), sD2[j], acc);
    }
    out[idx] = acc;
}

extern "C" void kernel_launch(void* const* d_in, const int* in_sizes, int n_in,
                              void* d_out, int out_size, void* d_ws, size_t ws_size,
                              hipStream_t stream) {
    const float* c_source   = (const float*)d_in[0];
    const float* c_target   = (const float*)d_in[1];
    const float* wavelength = (const float*)d_in[2];
    const float* W1 = (const float*)d_in[3];
    const float* b1 = (const float*)d_in[4];
    const float* W2 = (const float*)d_in[5];
    const float* b2 = (const float*)d_in[6];
    const float* W3 = (const float*)d_in[7];
    const float* b3 = (const float*)d_in[8];
    const float* D1 = (const float*)d_in[9];
    const float* d1 = (const float*)d_in[10];
    const float* D2 = (const float*)d_in[11];
    const float* d2 = (const float*)d_in[12];
    float* out = (float*)d_out;
    float* ws  = (float*)d_ws;

    const int n = in_sizes[0];

    hipLaunchKernelGGL(table_raw_kernel, dim3(RAW2 / 256), dim3(256), 0,
                       stream, W1, b1, W2, b2, W3, b3, ws);

    const int block = 256;
    const int grid  = (n + block - 1) / block;
    hipLaunchKernelGGL(geodesic_kernel, dim3(grid), dim3(block), 0, stream,
                       c_source, c_target, wavelength,
                       D1, d1, D2, d2, ws, out, n);
}